// Round 7
// baseline (285.201 us; speedup 1.0000x reference)
//
#include <hip/hip_runtime.h>

#define BATCH 65536
#define DIM 128
#define NPROTO 512
#define ODIM 8
#define CHUNKS 8
#define PPC (NPROTO / CHUNKS)   // 64 prototypes per chunk

// ---------------- prep: w[p][d] = proto[p][d] * rel[d]^2 ; psq[p] = sum_d rel^2 * proto^2
__global__ void grlvq_prep(const float* __restrict__ proto,
                           const float* __restrict__ rel,
                           float* __restrict__ w,
                           float* __restrict__ psq) {
    int p = blockIdx.x * blockDim.x + threadIdx.x;
    if (p >= NPROTO) return;
    float acc = 0.f;
    #pragma unroll 8
    for (int d = 0; d < DIM; ++d) {
        float r = rel[d];
        float r2 = r * r;
        float v = proto[p * DIM + d];
        w[p * DIM + d] = v * r2;
        acc = fmaf(r2 * v, v, acc);
    }
    psq[p] = acc;
}

// ---------------- chunk kernel: thread = (row, 64-proto chunk).
// __launch_bounds__(256,2): cap regalloc at 2 waves/EU (<=256 VGPR) so the
// 32xfloat4 x-row stays register-resident; steady-state inner loop is then
// pure v_fma_f32 (w arrives via scalar s_load pipe, wave-uniform address).
__global__ __launch_bounds__(256, 2) void grlvq_chunk(const float* __restrict__ x,
                                                      const float* __restrict__ w,
                                                      const float* __restrict__ psq,
                                                      float* __restrict__ score,
                                                      int* __restrict__ sidx) {
    const int b = blockIdx.x * 256 + threadIdx.x;
    const int chunk = blockIdx.y;
    const int pbase = chunk * PPC;

    const float4* xp = (const float4*)(x + (size_t)b * DIM);
    float4 xr[32];
    #pragma unroll
    for (int i = 0; i < 32; ++i) xr[i] = xp[i];

    float best = INFINITY;
    int bestIdx = pbase;

    for (int p0 = pbase; p0 < pbase + PPC; p0 += 8) {
        float acc[8];
        #pragma unroll
        for (int j = 0; j < 8; ++j) acc[j] = 0.f;

        const float* wbase = w + (size_t)p0 * DIM;
        #pragma unroll
        for (int i = 0; i < 32; ++i) {
            float4 xv = xr[i];
            #pragma unroll
            for (int j = 0; j < 8; ++j) {
                // wave-uniform address -> scalar s_load, SGPR operand to FMA
                float4 wv = *(const float4*)(wbase + (size_t)j * DIM + i * 4);
                acc[j] = fmaf(xv.x, wv.x, acc[j]);
                acc[j] = fmaf(xv.y, wv.y, acc[j]);
                acc[j] = fmaf(xv.z, wv.z, acc[j]);
                acc[j] = fmaf(xv.w, wv.w, acc[j]);
            }
        }

        #pragma unroll
        for (int j = 0; j < 8; ++j) {
            float s = psq[p0 + j] - 2.0f * acc[j];
            if (s < best) { best = s; bestIdx = p0 + j; }  // strict < => first-min
        }
    }

    score[(size_t)b * CHUNKS + chunk] = best;
    sidx [(size_t)b * CHUNKS + chunk] = bestIdx;
}

// ---------------- reduce + gather: pick global min over 8 chunk candidates
__global__ __launch_bounds__(256) void grlvq_reduce(const float* __restrict__ score,
                                                    const int* __restrict__ sidx,
                                                    const float* __restrict__ pout,
                                                    float* __restrict__ out) {
    const int b = blockIdx.x * 256 + threadIdx.x;
    float best = INFINITY;
    int bi = 0;
    #pragma unroll
    for (int c = 0; c < CHUNKS; ++c) {   // ascending chunk order => first-min tie rule
        float s = score[(size_t)b * CHUNKS + c];
        int id = sidx[(size_t)b * CHUNKS + c];
        if (s < best) { best = s; bi = id; }
    }
    const float4* po = (const float4*)(pout + (size_t)bi * ODIM);
    float4* op = (float4*)(out + (size_t)b * ODIM);
    op[0] = po[0];
    op[1] = po[1];
}

extern "C" void kernel_launch(void* const* d_in, const int* in_sizes, int n_in,
                              void* d_out, int out_size, void* d_ws, size_t ws_size,
                              hipStream_t stream) {
    const float* x     = (const float*)d_in[0];  // [BATCH, DIM]
    const float* proto = (const float*)d_in[1];  // [NPROTO, DIM]
    const float* pout  = (const float*)d_in[2];  // [NPROTO, ODIM]
    const float* rel   = (const float*)d_in[3];  // [DIM]
    float* out = (float*)d_out;                  // [BATCH, ODIM]

    float* w     = (float*)d_ws;                 // NPROTO*DIM floats      (256 KB)
    float* psq   = w + NPROTO * DIM;             // NPROTO floats
    float* score = psq + NPROTO;                 // BATCH*CHUNKS floats    (2 MB)
    int*   sidx  = (int*)(score + (size_t)BATCH * CHUNKS); // BATCH*CHUNKS ints (2 MB)

    grlvq_prep<<<(NPROTO + 255) / 256, 256, 0, stream>>>(proto, rel, w, psq);
    grlvq_chunk<<<dim3(BATCH / 256, CHUNKS), 256, 0, stream>>>(x, w, psq, score, sidx);
    grlvq_reduce<<<BATCH / 256, 256, 0, stream>>>(score, sidx, pout, out);
}

// Round 9
// 243.226 us; speedup vs baseline: 1.1726x; 1.1726x over previous
//
#include <hip/hip_runtime.h>

#define BATCH 65536
#define DIM 128
#define NPROTO 512
#define ODIM 8
#define CHUNKS 8
#define PPC (NPROTO / CHUNKS)   // 64 prototypes per chunk
#define DTILE 32                // dims per tile (8 x float4)

// ---------------- prep: w[p][d] = proto[p][d] * rel[d]^2 ; psq[p] = sum_d rel^2 * proto^2
__global__ void grlvq_prep(const float* __restrict__ proto,
                           const float* __restrict__ rel,
                           float* __restrict__ w,
                           float* __restrict__ psq) {
    int p = blockIdx.x * blockDim.x + threadIdx.x;
    if (p >= NPROTO) return;
    float acc = 0.f;
    #pragma unroll 8
    for (int d = 0; d < DIM; ++d) {
        float r = rel[d];
        float r2 = r * r;
        float v = proto[p * DIM + d];
        w[p * DIM + d] = v * r2;
        acc = fmaf(r2 * v, v, acc);
    }
    psq[p] = acc;
}

// ---------------- chunk kernel: thread = (row, 64-proto chunk), D-tiled.
// acc[64] statically indexed (fully unrolled p-loop) -> lives in VGPRs like a
// GEMM accumulator. x-tile (8 float4) lives only one tile iteration -> x is
// read exactly once per thread. w addresses are wave-uniform -> scalar s_load
// pipe feeds the FMAs via SGPR operands; steady state is ~pure v_fmac_f32.
__global__ __launch_bounds__(256, 4) void grlvq_chunk(const float* __restrict__ x,
                                                      const float* __restrict__ w,
                                                      const float* __restrict__ psq,
                                                      float* __restrict__ score,
                                                      int* __restrict__ sidx) {
    const int b = blockIdx.x * 256 + threadIdx.x;
    const int chunk = blockIdx.y;
    const int pbase = chunk * PPC;

    const float* xrow = x + (size_t)b * DIM;
    const float* wchunk = w + (size_t)pbase * DIM;

    float acc[PPC];
    #pragma unroll
    for (int p = 0; p < PPC; ++p) acc[p] = 0.f;

    #pragma unroll 1   // keep body ~12 KB; 4 iterations
    for (int t = 0; t < DIM; t += DTILE) {
        float4 xt[DTILE / 4];
        #pragma unroll
        for (int i = 0; i < DTILE / 4; ++i)
            xt[i] = *(const float4*)(xrow + t + i * 4);

        #pragma unroll
        for (int p = 0; p < PPC; ++p) {
            const float* wp = wchunk + (size_t)p * DIM + t;
            #pragma unroll
            for (int i = 0; i < DTILE / 4; ++i) {
                float4 wv = *(const float4*)(wp + i * 4);   // uniform -> s_load
                acc[p] = fmaf(xt[i].x, wv.x, acc[p]);
                acc[p] = fmaf(xt[i].y, wv.y, acc[p]);
                acc[p] = fmaf(xt[i].z, wv.z, acc[p]);
                acc[p] = fmaf(xt[i].w, wv.w, acc[p]);
            }
        }
    }

    float best = INFINITY;
    int bestIdx = pbase;
    #pragma unroll
    for (int p = 0; p < PPC; ++p) {
        float s = psq[pbase + p] - 2.0f * acc[p];
        if (s < best) { best = s; bestIdx = pbase + p; }  // strict < => first-min
    }

    score[(size_t)b * CHUNKS + chunk] = best;
    sidx [(size_t)b * CHUNKS + chunk] = bestIdx;
}

// ---------------- reduce + gather: pick global min over 8 chunk candidates
__global__ __launch_bounds__(256) void grlvq_reduce(const float* __restrict__ score,
                                                    const int* __restrict__ sidx,
                                                    const float* __restrict__ pout,
                                                    float* __restrict__ out) {
    const int b = blockIdx.x * 256 + threadIdx.x;
    float best = INFINITY;
    int bi = 0;
    #pragma unroll
    for (int c = 0; c < CHUNKS; ++c) {   // ascending chunk order => first-min tie rule
        float s = score[(size_t)b * CHUNKS + c];
        int id = sidx[(size_t)b * CHUNKS + c];
        if (s < best) { best = s; bi = id; }
    }
    const float4* po = (const float4*)(pout + (size_t)bi * ODIM);
    float4* op = (float4*)(out + (size_t)b * ODIM);
    op[0] = po[0];
    op[1] = po[1];
}

extern "C" void kernel_launch(void* const* d_in, const int* in_sizes, int n_in,
                              void* d_out, int out_size, void* d_ws, size_t ws_size,
                              hipStream_t stream) {
    const float* x     = (const float*)d_in[0];  // [BATCH, DIM]
    const float* proto = (const float*)d_in[1];  // [NPROTO, DIM]
    const float* pout  = (const float*)d_in[2];  // [NPROTO, ODIM]
    const float* rel   = (const float*)d_in[3];  // [DIM]
    float* out = (float*)d_out;                  // [BATCH, ODIM]

    float* w     = (float*)d_ws;                 // NPROTO*DIM floats      (256 KB)
    float* psq   = w + NPROTO * DIM;             // NPROTO floats
    float* score = psq + NPROTO;                 // BATCH*CHUNKS floats    (2 MB)
    int*   sidx  = (int*)(score + (size_t)BATCH * CHUNKS); // BATCH*CHUNKS ints (2 MB)

    grlvq_prep<<<(NPROTO + 255) / 256, 256, 0, stream>>>(proto, rel, w, psq);
    grlvq_chunk<<<dim3(BATCH / 256, CHUNKS), 256, 0, stream>>>(x, w, psq, score, sidx);
    grlvq_reduce<<<BATCH / 256, 256, 0, stream>>>(score, sidx, pout, out);
}

// Round 12
// 202.451 us; speedup vs baseline: 1.4087x; 1.2014x over previous
//
#include <hip/hip_runtime.h>

#define BATCH 65536
#define DIM 128
#define NPROTO 512
#define ODIM 8

#define ROWS 64            // rows (batch elements) per block; lane == row
#define THREADS 512        // 8 waves; wave w owns protos [w*64, w*64+64)
#define XSTRIDE 132        // 128 + 4 pad floats -> 33 x 16B units, conflict-free ds_read_b128

// wT layout: proto p = wb*64 + oo*8 + j   (wb=wave block 0..7, oo=octet 0..7, j=0..7)
//            dim   d = c*4 + d'           (c=chunk 0..31, d'=0..3)
// offset(p,d) = wb*8192 + oo*1024 + c*32 + j*4 + d'
// => per (wb,oo,c): 128 contiguous bytes holding 8 protos x 4 dims (scalar-load friendly)

// ---------------- prep: pack w = proto*rel^2 into wT; psq[p] = sum_d rel^2*proto^2
__global__ void grlvq_prep(const float* __restrict__ proto,
                           const float* __restrict__ rel,
                           float* __restrict__ wT,
                           float* __restrict__ psq) {
    int p = blockIdx.x * blockDim.x + threadIdx.x;
    if (p >= NPROTO) return;
    const int wb = p >> 6, oo = (p >> 3) & 7, j = p & 7;
    float acc = 0.f;
    #pragma unroll 8
    for (int d = 0; d < DIM; ++d) {
        float r = rel[d];
        float r2 = r * r;
        float v = proto[p * DIM + d];
        wT[wb * 8192 + oo * 1024 + (d >> 2) * 32 + j * 4 + (d & 3)] = v * r2;
        acc = fmaf(r2 * v, v, acc);   // same order as previous passing kernels
    }
    psq[p] = acc;
}

// ---------------- fused main: LDS x-tile, scalar-pipe w, in-block argmin + gather
__global__ __launch_bounds__(THREADS, 8) void grlvq_main(const float* __restrict__ x,
                                                         const float* __restrict__ wT,
                                                         const float* __restrict__ psq,
                                                         const float* __restrict__ pout,
                                                         float* __restrict__ out) {
    __shared__ float xs[ROWS * XSTRIDE];   // 33.8 KB
    __shared__ float red_s[ROWS * 8];      // per-wave best score
    __shared__ int   red_i[ROWS * 8];      // per-wave best index

    const int t = threadIdx.x;
    const int rowBase = blockIdx.x * ROWS;

    // stage x tile: 64 rows x 32 float4 = 2048 float4s; each of 512 threads loads 4
    #pragma unroll
    for (int k = 0; k < 4; ++k) {
        const int idx = t + k * THREADS;       // 0..2047
        const int r = idx >> 5, c = idx & 31;  // r in [0,64), c in [0,32)
        float4 v = *(const float4*)(x + (size_t)(rowBase + r) * DIM + c * 4);
        *(float4*)(&xs[r * XSTRIDE + c * 4]) = v;
    }
    __syncthreads();

    const int lane = t & 63;                                   // = row in tile
    const int wid  = __builtin_amdgcn_readfirstlane(t >> 6);   // SGPR -> uniform w addr
    const float* xrow  = &xs[lane * XSTRIDE];
    const float* wbase = wT + (size_t)wid * 8192;              // this wave's 64 protos
    const int pbase = wid * 64;

    float best = INFINITY;
    int bestIdx = pbase;

    #pragma unroll 1
    for (int oo = 0; oo < 8; ++oo) {                 // 8 octets of 8 protos
        float acc[8];
        #pragma unroll
        for (int j = 0; j < 8; ++j) acc[j] = 0.f;

        const float* wp = wbase + oo * 1024;
        #pragma unroll 4
        for (int c = 0; c < 32; ++c) {
            float4 xv = *(const float4*)(xrow + c * 4);   // ds_read_b128, stride 33x16B
            const float* wc = wp + c * 32;                // uniform -> s_load (128B)
            #pragma unroll
            for (int j = 0; j < 8; ++j) {
                acc[j] = fmaf(xv.x, wc[j * 4 + 0], acc[j]);
                acc[j] = fmaf(xv.y, wc[j * 4 + 1], acc[j]);
                acc[j] = fmaf(xv.z, wc[j * 4 + 2], acc[j]);
                acc[j] = fmaf(xv.w, wc[j * 4 + 3], acc[j]);
            }
        }

        #pragma unroll
        for (int j = 0; j < 8; ++j) {
            float s = psq[pbase + oo * 8 + j] - 2.0f * acc[j];
            if (s < best) { best = s; bestIdx = pbase + oo * 8 + j; }  // strict < ascending
        }
    }

    red_s[lane * 8 + wid] = best;
    red_i[lane * 8 + wid] = bestIdx;
    __syncthreads();

    if (t < ROWS) {                       // wave 0: lane = row
        float b = INFINITY;
        int bi = 0;
        #pragma unroll
        for (int w8 = 0; w8 < 8; ++w8) {  // ascending wave = ascending proto => first-min
            float s = red_s[t * 8 + w8];
            int  id = red_i[t * 8 + w8];
            if (s < b) { b = s; bi = id; }
        }
        const float4* po = (const float4*)(pout + (size_t)bi * ODIM);
        float4* op = (float4*)(out + (size_t)(rowBase + t) * ODIM);
        op[0] = po[0];
        op[1] = po[1];
    }
}

extern "C" void kernel_launch(void* const* d_in, const int* in_sizes, int n_in,
                              void* d_out, int out_size, void* d_ws, size_t ws_size,
                              hipStream_t stream) {
    const float* x     = (const float*)d_in[0];  // [BATCH, DIM]
    const float* proto = (const float*)d_in[1];  // [NPROTO, DIM]
    const float* pout  = (const float*)d_in[2];  // [NPROTO, ODIM]
    const float* rel   = (const float*)d_in[3];  // [DIM]
    float* out = (float*)d_out;                  // [BATCH, ODIM]

    float* wT  = (float*)d_ws;                   // NPROTO*DIM floats (256 KB)
    float* psq = wT + NPROTO * DIM;              // NPROTO floats

    grlvq_prep<<<(NPROTO + 127) / 128, 128, 0, stream>>>(proto, rel, wT, psq);
    grlvq_main<<<BATCH / ROWS, THREADS, 0, stream>>>(x, wT, psq, pout, out);
}